// Round 4
// baseline (463.231 us; speedup 1.0000x reference)
//
#include <hip/hip_runtime.h>
#include <cmath>

#define NN 100000   // nodes
#define FF 256      // feature dim
#define DDIM 128    // embedding dim
#define MM 10       // categories
#define BB 32768    // batch
#define KK 32       // neighbors
#define NB1 1563    // k1 blocks (64 rows each)

// workspace layout (float offsets)
#define OFF_Q    0            // [NN] q
#define OFF_PART 100096       // [NB1][1280] per-block ce partials
#define OFF_LAT  2100736      // [20][128] sigmoid lat table
#define OFF_WPP  2103296      // [128][128] perm-row (l1w[:128]+l1w[128:])
#define OFF_CE01 2119680      // [2][128] ce rows 0,1 in p-space
#define OFF_CS   2119936      // [2] c0,c1
#define OFF_AGG  2119952      // [BB][128] p-space
#define OFF_FE8  6314256      // [NN][128] bytes fp8 e4m3, p-space cols
#define OFF_WF   9514256      // W_emb bf16 hi/lo frags (65536 shorts)
// total 9,547,024 floats = 36.4 MiB

typedef __attribute__((ext_vector_type(8))) short bf16x8;
typedef __attribute__((ext_vector_type(4))) float floatx4;
typedef __attribute__((ext_vector_type(2))) float floatx2;

__device__ __forceinline__ unsigned short f2bf(float x) {
  union { float f; unsigned u; } v; v.f = x;
  unsigned r = v.u + 0x7FFFu + ((v.u >> 16) & 1u);   // RNE
  return (unsigned short)(r >> 16);
}
__device__ __forceinline__ float bf2f(unsigned short h) {
  union { float f; unsigned u; } v; v.u = ((unsigned)h) << 16;
  return v.f;
}

// ---------------------------------------------------------------------------
// k0: W_emb [256][128] fp32 -> fragment-linear bf16 hi/lo (16x16x32 B-operand)
// wf[h][kk][ct][lane][j]; element = W[kk*32 + (lane>>4)*8 + j][ct*16+(lane&15)]
// ---------------------------------------------------------------------------
__global__ __launch_bounds__(256) void k0_wprep(const float* __restrict__ wemb,
                                                short* __restrict__ wf)
{
  const int t = blockIdx.x * 256 + threadIdx.x;   // 0..4095
  const int kk = t >> 9, rem = t & 511;
  const int ct = rem >> 6, l = rem & 63;
  const int n = ct * 16 + (l & 15);
  const int kbase = kk * 32 + (l >> 4) * 8;
  short hi[8], lo[8];
#pragma unroll
  for (int j = 0; j < 8; j++) {
    const float x = wemb[(kbase + j) * 128 + n];
    const unsigned short h = f2bf(x);
    hi[j] = (short)h;
    lo[j] = (short)f2bf(x - bf2f(h));
  }
  const int off = ((kk * 8 + ct) * 64 + l) * 8;
  *reinterpret_cast<int4*>(&wf[off])         = *reinterpret_cast<int4*>(hi);
  *reinterpret_cast<int4*>(&wf[32768 + off]) = *reinterpret_cast<int4*>(lo);
}

__device__ __forceinline__ void split8v(float4 a, float4 b,
                                        bf16x8& hi8, bf16x8& lo8)
{
  const float xs[8] = {a.x, a.y, a.z, a.w, b.x, b.y, b.z, b.w};
  short h[8], l[8];
#pragma unroll
  for (int j = 0; j < 8; j++) {
    const unsigned short hh = f2bf(xs[j]);
    h[j] = (short)hh;
    l[j] = (short)f2bf(xs[j] - bf2f(hh));
  }
  hi8 = *reinterpret_cast<bf16x8*>(h);
  lo8 = *reinterpret_cast<bf16x8*>(l);
}

// ---------------------------------------------------------------------------
// K1 (fused): per block of 64 rows:
//  fe = feat @ W_emb + b_emb  (split-bf16 MFMA, 3 products)
//  q[n] = 0.5*dot(fe[n], attw)
//  fe8[n][p-space] e4m3, coalesced dwordx2 stores (perm p(c)=(c&15)*8+(c>>4))
//  ce partial [10][128] = adj_chunk @ fe_chunk  via bf16 MFMA on an LDS tile
// 128 thr = 2 waves; wave w owns rows [blk*64+32w, +32).
// ---------------------------------------------------------------------------
__global__ __launch_bounds__(128) void k1_fused(const float* __restrict__ feat,
    const short* __restrict__ wf, const float* __restrict__ bemb,
    const float* __restrict__ attw, const float* __restrict__ adj,
    float* __restrict__ q, unsigned char* __restrict__ fe8,
    float* __restrict__ part)
{
  __shared__ __align__(16) unsigned char ldst[128 * 144];  // bf16 tile [col][row0..63]
  const int tid = threadIdx.x;
  const int wv = tid >> 6, l = tid & 63;
  const int lane16 = l & 15, quad = l >> 4;
  const int rowbase = blockIdx.x * 64 + wv * 32;

  floatx4 acc[2][8];
#pragma unroll
  for (int rt = 0; rt < 2; rt++)
#pragma unroll
    for (int ct = 0; ct < 8; ct++) acc[rt][ct] = floatx4{0.f, 0.f, 0.f, 0.f};

  int r0 = rowbase + lane16;      if (r0 > NN - 1) r0 = NN - 1;
  int r1 = rowbase + 16 + lane16; if (r1 > NN - 1) r1 = NN - 1;
  const float* pa0 = &feat[(size_t)r0 * 256 + quad * 8];
  const float* pa1 = &feat[(size_t)r1 * 256 + quad * 8];

  float4 A0a = *reinterpret_cast<const float4*>(pa0);
  float4 A0b = *reinterpret_cast<const float4*>(pa0 + 4);
  float4 A1a = *reinterpret_cast<const float4*>(pa1);
  float4 A1b = *reinterpret_cast<const float4*>(pa1 + 4);

  for (int kk = 0; kk < 8; kk++) {
    float4 N0a, N0b, N1a, N1b;
    if (kk < 7) {
      N0a = *reinterpret_cast<const float4*>(pa0 + (kk + 1) * 32);
      N0b = *reinterpret_cast<const float4*>(pa0 + (kk + 1) * 32 + 4);
      N1a = *reinterpret_cast<const float4*>(pa1 + (kk + 1) * 32);
      N1b = *reinterpret_cast<const float4*>(pa1 + (kk + 1) * 32 + 4);
    }
    bf16x8 a0h, a0l, a1h, a1l;
    split8v(A0a, A0b, a0h, a0l);
    split8v(A1a, A1b, a1h, a1l);
    const short* wb = &wf[kk * 4096 + l * 8];
#pragma unroll
    for (int ct = 0; ct < 8; ct++) {
      const bf16x8 bh = *reinterpret_cast<const bf16x8*>(&wb[ct * 512]);
      const bf16x8 bl = *reinterpret_cast<const bf16x8*>(&wb[32768 + ct * 512]);
      acc[0][ct] = __builtin_amdgcn_mfma_f32_16x16x32_bf16(a0h, bh, acc[0][ct], 0, 0, 0);
      acc[1][ct] = __builtin_amdgcn_mfma_f32_16x16x32_bf16(a1h, bh, acc[1][ct], 0, 0, 0);
      acc[0][ct] = __builtin_amdgcn_mfma_f32_16x16x32_bf16(a0l, bh, acc[0][ct], 0, 0, 0);
      acc[1][ct] = __builtin_amdgcn_mfma_f32_16x16x32_bf16(a1l, bh, acc[1][ct], 0, 0, 0);
      acc[0][ct] = __builtin_amdgcn_mfma_f32_16x16x32_bf16(a0h, bl, acc[0][ct], 0, 0, 0);
      acc[1][ct] = __builtin_amdgcn_mfma_f32_16x16x32_bf16(a1h, bl, acc[1][ct], 0, 0, 0);
    }
    A0a = N0a; A0b = N0b; A1a = N1a; A1b = N1b;
  }

  // ---- epilogue: bias, q, fe8 (perm-packed), LDS bf16 tile ----
  // C layout: col = ct*16+lane16, row = rowbase + rt*16 + quad*4 + reg.
  float bembv[8], attwv[8];
#pragma unroll
  for (int ct = 0; ct < 8; ct++) {
    bembv[ct] = bemb[ct * 16 + lane16];
    attwv[ct] = attw[ct * 16 + lane16];
  }
#pragma unroll
  for (int rt = 0; rt < 2; rt++) {
#pragma unroll
    for (int reg = 0; reg < 4; reg++) {
      const int rloc = (rt * 16 + quad * 4 + reg) + wv * 32;   // block-local row
      const int r = blockIdx.x * 64 + rloc;
      float v[8]; float qp = 0.f;
#pragma unroll
      for (int ct = 0; ct < 8; ct++) {
        v[ct] = acc[rt][ct][reg] + bembv[ct];
        qp = fmaf(v[ct], attwv[ct], qp);
      }
      acc[rt][0][reg] = v[0]; acc[rt][1][reg] = v[1]; acc[rt][2][reg] = v[2]; acc[rt][3][reg] = v[3];
      acc[rt][4][reg] = v[4]; acc[rt][5][reg] = v[5]; acc[rt][6][reg] = v[6]; acc[rt][7][reg] = v[7];
      qp += __shfl_xor(qp, 1, 16);
      qp += __shfl_xor(qp, 2, 16);
      qp += __shfl_xor(qp, 4, 16);
      qp += __shfl_xor(qp, 8, 16);
      if (r < NN) {
        // fe8: bytes p = lane16*8 + ct  (p-space, coalesced)
        unsigned u0 = __builtin_amdgcn_cvt_pk_fp8_f32(v[0], v[1], 0, false);
        u0 = __builtin_amdgcn_cvt_pk_fp8_f32(v[2], v[3], u0, true);
        unsigned u1 = __builtin_amdgcn_cvt_pk_fp8_f32(v[4], v[5], 0, false);
        u1 = __builtin_amdgcn_cvt_pk_fp8_f32(v[6], v[7], u1, true);
        *reinterpret_cast<uint2*>(&fe8[(size_t)r * 128 + lane16 * 8]) = make_uint2(u0, u1);
        if (lane16 == 0) q[r] = 0.5f * qp;
      }
    }
  }
  // LDS bf16 tile [col][row], col stride 144 B; zero rows >= NN
#pragma unroll
  for (int rt = 0; rt < 2; rt++) {
#pragma unroll
    for (int rp = 0; rp < 2; rp++) {          // reg pairs (0,1),(2,3)
      const int rloc = wv * 32 + rt * 16 + quad * 4 + rp * 2;
      const int g0 = blockIdx.x * 64 + rloc;
#pragma unroll
      for (int ct = 0; ct < 8; ct++) {
        const unsigned short h0 = (g0     < NN) ? f2bf(acc[rt][ct][rp * 2])     : (unsigned short)0;
        const unsigned short h1 = (g0 + 1 < NN) ? f2bf(acc[rt][ct][rp * 2 + 1]) : (unsigned short)0;
        const unsigned pk = (unsigned)h0 | ((unsigned)h1 << 16);
        *reinterpret_cast<unsigned*>(&ldst[(ct * 16 + lane16) * 144 + rloc * 2]) = pk;
      }
    }
  }
  __syncthreads();

  // ce partial: [10(padded16)][128] = adj[., block rows] @ tile
  // A[m=lane16][k=quad*8+j] from adj (bf16); B[k][n=lane16] from LDS tile.
  floatx4 cacc[4];
#pragma unroll
  for (int tt = 0; tt < 4; tt++) cacc[tt] = floatx4{0.f, 0.f, 0.f, 0.f};
  const int mclamp = (lane16 < 10) ? lane16 : 9;
  for (int kc = 0; kc < 2; kc++) {
    int n0 = blockIdx.x * 64 + kc * 32 + quad * 8;
    if (n0 > NN - 8) n0 = NN - 8;               // clamped garbage x zero tile rows
    const float4 f0 = *reinterpret_cast<const float4*>(&adj[(size_t)mclamp * NN + n0]);
    const float4 f1 = *reinterpret_cast<const float4*>(&adj[(size_t)mclamp * NN + n0 + 4]);
    short af[8];
    af[0] = (short)f2bf(f0.x); af[1] = (short)f2bf(f0.y);
    af[2] = (short)f2bf(f0.z); af[3] = (short)f2bf(f0.w);
    af[4] = (short)f2bf(f1.x); af[5] = (short)f2bf(f1.y);
    af[6] = (short)f2bf(f1.z); af[7] = (short)f2bf(f1.w);
    const bf16x8 afr = *reinterpret_cast<bf16x8*>(af);
#pragma unroll
    for (int tt = 0; tt < 4; tt++) {
      const int col = (wv * 4 + tt) * 16 + lane16;
      const bf16x8 bfr = *reinterpret_cast<const bf16x8*>(
          &ldst[col * 144 + (kc * 32 + quad * 8) * 2]);
      cacc[tt] = __builtin_amdgcn_mfma_f32_16x16x32_bf16(afr, bfr, cacc[tt], 0, 0, 0);
    }
  }
#pragma unroll
  for (int tt = 0; tt < 4; tt++) {
#pragma unroll
    for (int reg = 0; reg < 4; reg++) {
      const int m = quad * 4 + reg;
      if (m < 10)
        part[(size_t)blockIdx.x * 1280 + m * 128 + (wv * 4 + tt) * 16 + lane16] = cacc[tt][reg];
    }
  }
}

// ---------------------------------------------------------------------------
// fp32 register-blocked GEMM core (k4b)
// ---------------------------------------------------------------------------
template<int NCHUNK>
__device__ __forceinline__ void gemm_main(const float* __restrict__ A, int lda, int rowclamp,
                                          const float* __restrict__ W,
                                          int rowbase, int tid,
                                          float (*AT)[128], float (*WT)[128],
                                          float (&acc)[8][8])
{
  const int a_r  = tid >> 4;
  const int a_f4 = tid & 15;
  const int w_k  = tid >> 5;
  const int w_f4 = tid & 31;
  const int tx = tid & 15, ty = tid >> 4;

#pragma unroll
  for (int i = 0; i < 8; i++)
#pragma unroll
    for (int j = 0; j < 8; j++) acc[i][j] = 0.f;

  for (int cc = 0; cc < NCHUNK; cc++) {
    const int kc = cc * 64;
#pragma unroll
    for (int i = 0; i < 8; i++) {
      int r = a_r + 16 * i;
      int gr = rowbase + r; gr = (gr > rowclamp) ? rowclamp : gr;
      const float4 v = *reinterpret_cast<const float4*>(&A[gr * lda + kc + a_f4 * 4]);
      const int X = a_f4 * 4;
      const int col = r ^ X;
      AT[X + 0][col] = v.x;
      AT[X + 1][col] = v.y;
      AT[X + 2][col] = v.z;
      AT[X + 3][col] = v.w;
    }
#pragma unroll
    for (int i = 0; i < 8; i++) {
      const int k = w_k + 8 * i;
      *reinterpret_cast<float4*>(&WT[k][w_f4 * 4]) =
          *reinterpret_cast<const float4*>(&W[(kc + k) * 128 + w_f4 * 4]);
    }
    __syncthreads();
#pragma unroll 8
    for (int k = 0; k < 64; k++) {
      const int X = k & 60;
      const float4 va0 = *reinterpret_cast<const float4*>(&AT[k][(ty * 4) ^ X]);
      const float4 va1 = *reinterpret_cast<const float4*>(&AT[k][((ty * 4) ^ X) + 64]);
      const float4 vb0 = *reinterpret_cast<const float4*>(&WT[k][tx * 4]);
      const float4 vb1 = *reinterpret_cast<const float4*>(&WT[k][tx * 4 + 64]);
      const float a[8] = {va0.x, va0.y, va0.z, va0.w, va1.x, va1.y, va1.z, va1.w};
      const float b[8] = {vb0.x, vb0.y, vb0.z, vb0.w, vb1.x, vb1.y, vb1.z, vb1.w};
#pragma unroll
      for (int i = 0; i < 8; i++)
#pragma unroll
        for (int j = 0; j < 8; j++)
          acc[i][j] = fmaf(a[i], b[j], acc[i][j]);
    }
    __syncthreads();
  }
}

// K3: reduce ce partials; blocks 0..19 lat rows; block 20: ce01p, cs, Wpp(perm)
__global__ __launch_bounds__(128) void k3_prep(const float* __restrict__ part,
    const float* __restrict__ wchar, const float* __restrict__ attw,
    const float* __restrict__ l1w,
    float* __restrict__ latTab, float* __restrict__ Wpp,
    float* __restrict__ ce01p, float* __restrict__ cs)
{
  const int blk = blockIdx.x, tid = threadIdx.x;
  __shared__ float cec[128], cep[128];
  if (blk < 20) {
    const int c = blk / 10, p = blk % 10;
    float sc_ = 0.f, sp_ = 0.f;
    for (int pp = 0; pp < NB1; pp++) {
      sc_ += part[(size_t)pp * 1280 + c * 128 + tid];
      sp_ += part[(size_t)pp * 1280 + p * 128 + tid];
    }
    cec[tid] = sc_; cep[tid] = sp_;
    __syncthreads();
    float s = 0.f;
#pragma unroll 4
    for (int j = 0; j < 128; j++) {
      s = fmaf(cec[j], wchar[j * 128 + tid], s);
      s = fmaf(cep[j], wchar[(128 + j) * 128 + tid], s);
    }
    latTab[blk * 128 + tid] = 1.f / (1.f + expf(-s));
  } else {
    float s0 = 0.f, s1 = 0.f;
    for (int pp = 0; pp < NB1; pp++) {
      s0 += part[(size_t)pp * 1280 + tid];
      s1 += part[(size_t)pp * 1280 + 128 + tid];
    }
    const int pidx = (tid & 15) * 8 + (tid >> 4);   // p(c)
    ce01p[pidx] = s0;
    ce01p[128 + pidx] = s1;
    cec[tid] = s0 * attw[tid];
    cep[tid] = s1 * attw[tid];
    __syncthreads();
    if (tid < 64) {
      float p0 = cec[tid] + cec[tid + 64];
      float p1 = cep[tid] + cep[tid + 64];
#pragma unroll
      for (int off = 32; off >= 1; off >>= 1) {
        p0 += __shfl_xor(p0, off);
        p1 += __shfl_xor(p1, off);
      }
      if (tid == 0) { cs[0] = 0.5f * p0; cs[1] = 0.5f * p1; }
    }
    for (int i = 0; i < 128; i++) {
      const int pi = (i & 15) * 8 + (i >> 4);       // p(i): permuted k-row
      Wpp[pi * 128 + tid] = l1w[i * 128 + tid] + l1w[16384 + i * 128 + tid];
    }
  }
}

// ---------------------------------------------------------------------------
// K4a: softmax over 32 neighbor scores + fp8 weighted row gather (p-space).
// One half-wave per b; lane t covers p-cols 4t..4t+3 (one uint). Scores fp32.
// ---------------------------------------------------------------------------
__global__ __launch_bounds__(256) void k4a_attn(const unsigned char* __restrict__ fe8,
    const float* __restrict__ q, const float* __restrict__ adj,
    const int* __restrict__ history, const float* __restrict__ cs,
    const float* __restrict__ attb_p, const float* __restrict__ ce01p,
    float* __restrict__ agg)
{
  const int tid = threadIdx.x;
  const int lane = tid & 63;
  const int wv = tid >> 6;
  const int half = lane >> 5;
  const int t = lane & 31;
  const int b = blockIdx.x * 8 + wv * 2 + half;

  const int n_my = history[b * 32 + t];
  const float a0 = adj[n_my];
  const float a1 = adj[NN + n_my];
  const float sc = q[n_my] + a0 * cs[0] + a1 * cs[1] + attb_p[0];
  float m = sc;
#pragma unroll
  for (int off = 16; off >= 1; off >>= 1) m = fmaxf(m, __shfl_xor(m, off, 32));
  const float e = expf(sc - m);
  float sum = e;
#pragma unroll
  for (int off = 16; off >= 1; off >>= 1) sum += __shfl_xor(sum, off, 32);
  const float att = e / sum;
  float p0 = att * a0, p1 = att * a1;
#pragma unroll
  for (int off = 16; off >= 1; off >>= 1) {
    p0 += __shfl_xor(p0, off, 32);
    p1 += __shfl_xor(p1, off, 32);
  }

  float4 acc = make_float4(0.f, 0.f, 0.f, 0.f);
#pragma unroll
  for (int k = 0; k < 32; k++) {
    const int nk = __shfl(n_my, k, 32);
    const float ak = __shfl(att, k, 32);
    const unsigned u = *reinterpret_cast<const unsigned*>(&fe8[(size_t)nk * 128 + t * 4]);
    const floatx2 lo = __builtin_amdgcn_cvt_pk_f32_fp8(u, false);
    const floatx2 hi = __builtin_amdgcn_cvt_pk_f32_fp8(u, true);
    acc.x = fmaf(ak, lo[0], acc.x);
    acc.y = fmaf(ak, lo[1], acc.y);
    acc.z = fmaf(ak, hi[0], acc.z);
    acc.w = fmaf(ak, hi[1], acc.w);
  }
  const int col = t * 4;
  const float4 c0 = *reinterpret_cast<const float4*>(&ce01p[col]);
  const float4 c1 = *reinterpret_cast<const float4*>(&ce01p[128 + col]);
  float4 o;
  o.x = 0.5f * (acc.x + p0 * c0.x + p1 * c1.x);
  o.y = 0.5f * (acc.y + p0 * c0.y + p1 * c1.y);
  o.z = 0.5f * (acc.z + p0 * c0.z + p1 * c1.z);
  o.w = 0.5f * (acc.w + p0 * c0.w + p1 * c1.w);
  *reinterpret_cast<float4*>(&agg[(size_t)b * 128 + col]) = o;
}

// K4b: out = relu(aggP @ Wpp + l1b); preds vs latTab rows (k in p-space)
__global__ __launch_bounds__(256) void k4b_out(const float* __restrict__ agg,
    const float* __restrict__ Wpp, const float* __restrict__ l1b,
    const float* __restrict__ latTab,
    const int* __restrict__ cr, const int* __restrict__ cn, const int* __restrict__ pa,
    float* __restrict__ out)
{
  __shared__ __align__(16) float AT[64][128];
  __shared__ __align__(16) float WT[64][128];
  const int tid = threadIdx.x;
  const int tx = tid & 15, ty = tid >> 4;
  const int rowbase = blockIdx.x * 128;
  float acc[8][8];
  gemm_main<2>(agg, 128, BB - 1, Wpp, rowbase, tid, AT, WT, acc);

  int* latIdx = reinterpret_cast<int*>(&AT[0][0]);
  if (tid < 128) {
    const int b = rowbase + tid;
    latIdx[tid * 2]     = (cr[b] * 10 + pa[b]) * 128;
    latIdx[tid * 2 + 1] = (cn[b] * 10 + pa[b]) * 128;
  }
  __syncthreads();

  const float4 b0 = *reinterpret_cast<const float4*>(&l1b[tx * 4]);
  const float4 b1 = *reinterpret_cast<const float4*>(&l1b[tx * 4 + 64]);
  const float bb[8] = {b0.x, b0.y, b0.z, b0.w, b1.x, b1.y, b1.z, b1.w};
#pragma unroll
  for (int i = 0; i < 8; i++) {
    const int r = (i < 4) ? (ty * 4 + i) : (64 + ty * 4 + (i - 4));
    const int b = rowbase + r;
    const int ir = latIdx[r * 2], in_ = latIdx[r * 2 + 1];
    const float4 lr0 = *reinterpret_cast<const float4*>(&latTab[ir + tx * 4]);
    const float4 lr1 = *reinterpret_cast<const float4*>(&latTab[ir + tx * 4 + 64]);
    const float4 ln0 = *reinterpret_cast<const float4*>(&latTab[in_ + tx * 4]);
    const float4 ln1 = *reinterpret_cast<const float4*>(&latTab[in_ + tx * 4 + 64]);
    const float lr[8] = {lr0.x, lr0.y, lr0.z, lr0.w, lr1.x, lr1.y, lr1.z, lr1.w};
    const float ln[8] = {ln0.x, ln0.y, ln0.z, ln0.w, ln1.x, ln1.y, ln1.z, ln1.w};
    float pr = 0.f, pn = 0.f;
#pragma unroll
    for (int j = 0; j < 8; j++) {
      const float v = fmaxf(acc[i][j] + bb[j], 0.f);
      pr = fmaf(v, lr[j], pr);
      pn = fmaf(v, ln[j], pn);
    }
    pr += __shfl_down(pr, 8, 16); pr += __shfl_down(pr, 4, 16);
    pr += __shfl_down(pr, 2, 16); pr += __shfl_down(pr, 1, 16);
    pn += __shfl_down(pn, 8, 16); pn += __shfl_down(pn, 4, 16);
    pn += __shfl_down(pn, 2, 16); pn += __shfl_down(pn, 1, 16);
    if (tx == 0) { out[b] = pr; out[BB + b] = pn; }
  }
}

extern "C" void kernel_launch(void* const* d_in, const int* in_sizes, int n_in,
                              void* d_out, int out_size, void* d_ws, size_t ws_size,
                              hipStream_t stream) {
  const float* feat  = (const float*)d_in[0];   // [N,F]
  const float* adj   = (const float*)d_in[1];   // [M,N]
  const int*   hist  = (const int*)d_in[2];     // [B,K]
  // d_in[3] item_id unused by reference
  const int*   cr    = (const int*)d_in[4];
  const int*   cn    = (const int*)d_in[5];
  const int*   pa    = (const int*)d_in[6];
  const float* wemb  = (const float*)d_in[7];   // [F,D]
  const float* bemb  = (const float*)d_in[8];   // [D]
  const float* wchar = (const float*)d_in[9];   // [2D,D]
  const float* attw  = (const float*)d_in[10];  // [D]
  const float* attb  = (const float*)d_in[11];  // [1]
  const float* l1w   = (const float*)d_in[12];  // [2D,D]
  const float* l1b   = (const float*)d_in[13];  // [D]
  float* out = (float*)d_out;
  float* ws  = (float*)d_ws;

  float* q     = ws + OFF_Q;
  float* part  = ws + OFF_PART;
  float* lat   = ws + OFF_LAT;
  float* Wpp   = ws + OFF_WPP;
  float* ce01p = ws + OFF_CE01;
  float* cs    = ws + OFF_CS;
  float* agg   = ws + OFF_AGG;
  unsigned char* fe8 = (unsigned char*)(ws + OFF_FE8);
  short* wf    = (short*)(ws + OFF_WF);

  k0_wprep<<<16, 256, 0, stream>>>(wemb, wf);
  k1_fused<<<NB1, 128, 0, stream>>>(feat, wf, bemb, attw, adj, q, fe8, part);
  k3_prep<<<21, 128, 0, stream>>>(part, wchar, attw, l1w, lat, Wpp, ce01p, cs);
  k4a_attn<<<4096, 256, 0, stream>>>(fe8, q, adj, hist, cs, attb, ce01p, agg);
  k4b_out<<<256, 256, 0, stream>>>(agg, Wpp, l1b, lat, cr, cn, pa, out);
}

// Round 5
// 311.262 us; speedup vs baseline: 1.4882x; 1.4882x over previous
//
#include <hip/hip_runtime.h>
#include <cmath>

#define NN 100000   // nodes
#define FF 256      // feature dim
#define DDIM 128    // embedding dim
#define MM 10       // categories
#define BB 32768    // batch
#define KK 32       // neighbors
#define NB1 1563    // k1 blocks (64 rows each)

// workspace layout (float offsets)
#define OFF_Q    0            // [NN] q
#define OFF_CE   100096       // [10][128] ce (atomic-accumulated), zeroed via memset
#define OFF_LAT  101376       // [20][128] sigmoid lat table
#define OFF_WPP  103936       // [128][128] perm-row (l1w[:128]+l1w[128:])
#define OFF_CE01 120320       // [2][128] ce rows 0,1 in p-space
#define OFF_CS   120576       // [2] c0,c1
#define OFF_AGG  120592       // [BB][128] p-space
#define OFF_FE8  4314896      // [NN][128] bytes fp8 e4m3, p-space cols
#define OFF_WF   7514896      // W_emb bf16 hi/lo frags (65536 shorts)
// total 7,547,664 floats = 28.8 MiB

typedef __attribute__((ext_vector_type(8))) short bf16x8;
typedef __attribute__((ext_vector_type(4))) float floatx4;
typedef __attribute__((ext_vector_type(2))) float floatx2;

__device__ __forceinline__ unsigned short f2bf(float x) {
  union { float f; unsigned u; } v; v.f = x;
  unsigned r = v.u + 0x7FFFu + ((v.u >> 16) & 1u);   // RNE
  return (unsigned short)(r >> 16);
}
__device__ __forceinline__ float bf2f(unsigned short h) {
  union { float f; unsigned u; } v; v.u = ((unsigned)h) << 16;
  return v.f;
}

// ---------------------------------------------------------------------------
// k0: W_emb [256][128] fp32 -> fragment-linear bf16 hi/lo (16x16x32 B-operand)
// wf[h][kk][ct][lane][j]; element = W[kk*32 + (lane>>4)*8 + j][ct*16+(lane&15)]
// ---------------------------------------------------------------------------
__global__ __launch_bounds__(256) void k0_wprep(const float* __restrict__ wemb,
                                                short* __restrict__ wf)
{
  const int t = blockIdx.x * 256 + threadIdx.x;   // 0..4095
  const int kk = t >> 9, rem = t & 511;
  const int ct = rem >> 6, l = rem & 63;
  const int n = ct * 16 + (l & 15);
  const int kbase = kk * 32 + (l >> 4) * 8;
  short hi[8], lo[8];
#pragma unroll
  for (int j = 0; j < 8; j++) {
    const float x = wemb[(kbase + j) * 128 + n];
    const unsigned short h = f2bf(x);
    hi[j] = (short)h;
    lo[j] = (short)f2bf(x - bf2f(h));
  }
  const int off = ((kk * 8 + ct) * 64 + l) * 8;
  *reinterpret_cast<int4*>(&wf[off])         = *reinterpret_cast<int4*>(hi);
  *reinterpret_cast<int4*>(&wf[32768 + off]) = *reinterpret_cast<int4*>(lo);
}

__device__ __forceinline__ void split8v(float4 a, float4 b,
                                        bf16x8& hi8, bf16x8& lo8)
{
  const float xs[8] = {a.x, a.y, a.z, a.w, b.x, b.y, b.z, b.w};
  short h[8], l[8];
#pragma unroll
  for (int j = 0; j < 8; j++) {
    const unsigned short hh = f2bf(xs[j]);
    h[j] = (short)hh;
    l[j] = (short)f2bf(xs[j] - bf2f(hh));
  }
  hi8 = *reinterpret_cast<bf16x8*>(h);
  lo8 = *reinterpret_cast<bf16x8*>(l);
}

// ---------------------------------------------------------------------------
// K1 (fused): per block of 64 rows:
//  fe = feat @ W_emb + b_emb  (split-bf16 MFMA, 3 products)
//  q[n] = 0.5*dot(fe[n], attw)
//  fe8[n][p-space] e4m3, coalesced dwordx2 stores (perm p(c)=(c&15)*8+(c>>4))
//  ce += adj_chunk @ fe_chunk  via bf16 MFMA on an LDS tile, global atomicAdd
// 128 thr = 2 waves; wave w owns rows [blk*64+32w, +32).
// ---------------------------------------------------------------------------
__global__ __launch_bounds__(128) void k1_fused(const float* __restrict__ feat,
    const short* __restrict__ wf, const float* __restrict__ bemb,
    const float* __restrict__ attw, const float* __restrict__ adj,
    float* __restrict__ q, unsigned char* __restrict__ fe8,
    float* __restrict__ ce)
{
  __shared__ __align__(16) unsigned char ldst[128 * 144];  // bf16 tile [col][row0..63]
  const int tid = threadIdx.x;
  const int wv = tid >> 6, l = tid & 63;
  const int lane16 = l & 15, quad = l >> 4;
  const int rowbase = blockIdx.x * 64 + wv * 32;

  floatx4 acc[2][8];
#pragma unroll
  for (int rt = 0; rt < 2; rt++)
#pragma unroll
    for (int ct = 0; ct < 8; ct++) acc[rt][ct] = floatx4{0.f, 0.f, 0.f, 0.f};

  int r0 = rowbase + lane16;      if (r0 > NN - 1) r0 = NN - 1;
  int r1 = rowbase + 16 + lane16; if (r1 > NN - 1) r1 = NN - 1;
  const float* pa0 = &feat[(size_t)r0 * 256 + quad * 8];
  const float* pa1 = &feat[(size_t)r1 * 256 + quad * 8];

  float4 A0a = *reinterpret_cast<const float4*>(pa0);
  float4 A0b = *reinterpret_cast<const float4*>(pa0 + 4);
  float4 A1a = *reinterpret_cast<const float4*>(pa1);
  float4 A1b = *reinterpret_cast<const float4*>(pa1 + 4);

  for (int kk = 0; kk < 8; kk++) {
    float4 N0a, N0b, N1a, N1b;
    if (kk < 7) {
      N0a = *reinterpret_cast<const float4*>(pa0 + (kk + 1) * 32);
      N0b = *reinterpret_cast<const float4*>(pa0 + (kk + 1) * 32 + 4);
      N1a = *reinterpret_cast<const float4*>(pa1 + (kk + 1) * 32);
      N1b = *reinterpret_cast<const float4*>(pa1 + (kk + 1) * 32 + 4);
    }
    bf16x8 a0h, a0l, a1h, a1l;
    split8v(A0a, A0b, a0h, a0l);
    split8v(A1a, A1b, a1h, a1l);
    const short* wb = &wf[kk * 4096 + l * 8];
#pragma unroll
    for (int ct = 0; ct < 8; ct++) {
      const bf16x8 bh = *reinterpret_cast<const bf16x8*>(&wb[ct * 512]);
      const bf16x8 bl = *reinterpret_cast<const bf16x8*>(&wb[32768 + ct * 512]);
      acc[0][ct] = __builtin_amdgcn_mfma_f32_16x16x32_bf16(a0h, bh, acc[0][ct], 0, 0, 0);
      acc[1][ct] = __builtin_amdgcn_mfma_f32_16x16x32_bf16(a1h, bh, acc[1][ct], 0, 0, 0);
      acc[0][ct] = __builtin_amdgcn_mfma_f32_16x16x32_bf16(a0l, bh, acc[0][ct], 0, 0, 0);
      acc[1][ct] = __builtin_amdgcn_mfma_f32_16x16x32_bf16(a1l, bh, acc[1][ct], 0, 0, 0);
      acc[0][ct] = __builtin_amdgcn_mfma_f32_16x16x32_bf16(a0h, bl, acc[0][ct], 0, 0, 0);
      acc[1][ct] = __builtin_amdgcn_mfma_f32_16x16x32_bf16(a1h, bl, acc[1][ct], 0, 0, 0);
    }
    A0a = N0a; A0b = N0b; A1a = N1a; A1b = N1b;
  }

  // ---- epilogue: bias, q, fe8 (perm-packed), LDS bf16 tile ----
  // C layout: col = ct*16+lane16, row = rowbase + rt*16 + quad*4 + reg.
  float bembv[8], attwv[8];
#pragma unroll
  for (int ct = 0; ct < 8; ct++) {
    bembv[ct] = bemb[ct * 16 + lane16];
    attwv[ct] = attw[ct * 16 + lane16];
  }
#pragma unroll
  for (int rt = 0; rt < 2; rt++) {
#pragma unroll
    for (int reg = 0; reg < 4; reg++) {
      const int rloc = (rt * 16 + quad * 4 + reg) + wv * 32;   // block-local row
      const int r = blockIdx.x * 64 + rloc;
      float v[8]; float qp = 0.f;
#pragma unroll
      for (int ct = 0; ct < 8; ct++) {
        v[ct] = acc[rt][ct][reg] + bembv[ct];
        qp = fmaf(v[ct], attwv[ct], qp);
      }
      acc[rt][0][reg] = v[0]; acc[rt][1][reg] = v[1]; acc[rt][2][reg] = v[2]; acc[rt][3][reg] = v[3];
      acc[rt][4][reg] = v[4]; acc[rt][5][reg] = v[5]; acc[rt][6][reg] = v[6]; acc[rt][7][reg] = v[7];
      qp += __shfl_xor(qp, 1, 16);
      qp += __shfl_xor(qp, 2, 16);
      qp += __shfl_xor(qp, 4, 16);
      qp += __shfl_xor(qp, 8, 16);
      if (r < NN) {
        // fe8: bytes p = lane16*8 + ct  (p-space, coalesced)
        unsigned u0 = __builtin_amdgcn_cvt_pk_fp8_f32(v[0], v[1], 0, false);
        u0 = __builtin_amdgcn_cvt_pk_fp8_f32(v[2], v[3], u0, true);
        unsigned u1 = __builtin_amdgcn_cvt_pk_fp8_f32(v[4], v[5], 0, false);
        u1 = __builtin_amdgcn_cvt_pk_fp8_f32(v[6], v[7], u1, true);
        *reinterpret_cast<uint2*>(&fe8[(size_t)r * 128 + lane16 * 8]) = make_uint2(u0, u1);
        if (lane16 == 0) q[r] = 0.5f * qp;
      }
    }
  }
  // LDS bf16 tile [col][row], col stride 144 B; zero rows >= NN
#pragma unroll
  for (int rt = 0; rt < 2; rt++) {
#pragma unroll
    for (int rp = 0; rp < 2; rp++) {          // reg pairs (0,1),(2,3)
      const int rloc = wv * 32 + rt * 16 + quad * 4 + rp * 2;
      const int g0 = blockIdx.x * 64 + rloc;
#pragma unroll
      for (int ct = 0; ct < 8; ct++) {
        const unsigned short h0 = (g0     < NN) ? f2bf(acc[rt][ct][rp * 2])     : (unsigned short)0;
        const unsigned short h1 = (g0 + 1 < NN) ? f2bf(acc[rt][ct][rp * 2 + 1]) : (unsigned short)0;
        const unsigned pk = (unsigned)h0 | ((unsigned)h1 << 16);
        *reinterpret_cast<unsigned*>(&ldst[(ct * 16 + lane16) * 144 + rloc * 2]) = pk;
      }
    }
  }
  __syncthreads();

  // ce partial: [10(padded16)][128] = adj[., block rows] @ tile -> global atomicAdd
  // A[m=lane16][k=quad*8+j] from adj (bf16); B[k][n=lane16] from LDS tile.
  floatx4 cacc[4];
#pragma unroll
  for (int tt = 0; tt < 4; tt++) cacc[tt] = floatx4{0.f, 0.f, 0.f, 0.f};
  const int mclamp = (lane16 < 10) ? lane16 : 9;
  for (int kc = 0; kc < 2; kc++) {
    int n0 = blockIdx.x * 64 + kc * 32 + quad * 8;
    if (n0 > NN - 8) n0 = NN - 8;               // clamped garbage x zero tile rows
    const float4 f0 = *reinterpret_cast<const float4*>(&adj[(size_t)mclamp * NN + n0]);
    const float4 f1 = *reinterpret_cast<const float4*>(&adj[(size_t)mclamp * NN + n0 + 4]);
    short af[8];
    af[0] = (short)f2bf(f0.x); af[1] = (short)f2bf(f0.y);
    af[2] = (short)f2bf(f0.z); af[3] = (short)f2bf(f0.w);
    af[4] = (short)f2bf(f1.x); af[5] = (short)f2bf(f1.y);
    af[6] = (short)f2bf(f1.z); af[7] = (short)f2bf(f1.w);
    const bf16x8 afr = *reinterpret_cast<bf16x8*>(af);
#pragma unroll
    for (int tt = 0; tt < 4; tt++) {
      const int col = (wv * 4 + tt) * 16 + lane16;
      const bf16x8 bfr = *reinterpret_cast<const bf16x8*>(
          &ldst[col * 144 + (kc * 32 + quad * 8) * 2]);
      cacc[tt] = __builtin_amdgcn_mfma_f32_16x16x32_bf16(afr, bfr, cacc[tt], 0, 0, 0);
    }
  }
#pragma unroll
  for (int tt = 0; tt < 4; tt++) {
#pragma unroll
    for (int reg = 0; reg < 4; reg++) {
      const int m = quad * 4 + reg;
      if (m < 10)
        atomicAdd(&ce[m * 128 + (wv * 4 + tt) * 16 + lane16], cacc[tt][reg]);
    }
  }
}

// ---------------------------------------------------------------------------
// fp32 register-blocked GEMM core (k4b)
// ---------------------------------------------------------------------------
template<int NCHUNK>
__device__ __forceinline__ void gemm_main(const float* __restrict__ A, int lda, int rowclamp,
                                          const float* __restrict__ W,
                                          int rowbase, int tid,
                                          float (*AT)[128], float (*WT)[128],
                                          float (&acc)[8][8])
{
  const int a_r  = tid >> 4;
  const int a_f4 = tid & 15;
  const int w_k  = tid >> 5;
  const int w_f4 = tid & 31;
  const int tx = tid & 15, ty = tid >> 4;

#pragma unroll
  for (int i = 0; i < 8; i++)
#pragma unroll
    for (int j = 0; j < 8; j++) acc[i][j] = 0.f;

  for (int cc = 0; cc < NCHUNK; cc++) {
    const int kc = cc * 64;
#pragma unroll
    for (int i = 0; i < 8; i++) {
      int r = a_r + 16 * i;
      int gr = rowbase + r; gr = (gr > rowclamp) ? rowclamp : gr;
      const float4 v = *reinterpret_cast<const float4*>(&A[gr * lda + kc + a_f4 * 4]);
      const int X = a_f4 * 4;
      const int col = r ^ X;
      AT[X + 0][col] = v.x;
      AT[X + 1][col] = v.y;
      AT[X + 2][col] = v.z;
      AT[X + 3][col] = v.w;
    }
#pragma unroll
    for (int i = 0; i < 8; i++) {
      const int k = w_k + 8 * i;
      *reinterpret_cast<float4*>(&WT[k][w_f4 * 4]) =
          *reinterpret_cast<const float4*>(&W[(kc + k) * 128 + w_f4 * 4]);
    }
    __syncthreads();
#pragma unroll 8
    for (int k = 0; k < 64; k++) {
      const int X = k & 60;
      const float4 va0 = *reinterpret_cast<const float4*>(&AT[k][(ty * 4) ^ X]);
      const float4 va1 = *reinterpret_cast<const float4*>(&AT[k][((ty * 4) ^ X) + 64]);
      const float4 vb0 = *reinterpret_cast<const float4*>(&WT[k][tx * 4]);
      const float4 vb1 = *reinterpret_cast<const float4*>(&WT[k][tx * 4 + 64]);
      const float a[8] = {va0.x, va0.y, va0.z, va0.w, va1.x, va1.y, va1.z, va1.w};
      const float b[8] = {vb0.x, vb0.y, vb0.z, vb0.w, vb1.x, vb1.y, vb1.z, vb1.w};
#pragma unroll
      for (int i = 0; i < 8; i++)
#pragma unroll
        for (int j = 0; j < 8; j++)
          acc[i][j] = fmaf(a[i], b[j], acc[i][j]);
    }
    __syncthreads();
  }
}

// K3: blocks 0..19 lat rows from ce (L2-hot, 5 KB); block 20: ce01p, cs, Wpp
__global__ __launch_bounds__(128) void k3_prep(const float* __restrict__ ce,
    const float* __restrict__ wchar, const float* __restrict__ attw,
    const float* __restrict__ l1w,
    float* __restrict__ latTab, float* __restrict__ Wpp,
    float* __restrict__ ce01p, float* __restrict__ cs)
{
  const int blk = blockIdx.x, tid = threadIdx.x;
  __shared__ float cec[128], cep[128];
  if (blk < 20) {
    const int c = blk / 10, p = blk % 10;
    cec[tid] = ce[c * 128 + tid];
    cep[tid] = ce[p * 128 + tid];
    __syncthreads();
    float s = 0.f;
#pragma unroll 4
    for (int j = 0; j < 128; j++) {
      s = fmaf(cec[j], wchar[j * 128 + tid], s);
      s = fmaf(cep[j], wchar[(128 + j) * 128 + tid], s);
    }
    latTab[blk * 128 + tid] = 1.f / (1.f + expf(-s));
  } else {
    const float s0 = ce[tid];
    const float s1 = ce[128 + tid];
    const int pidx = (tid & 15) * 8 + (tid >> 4);   // p(c)
    ce01p[pidx] = s0;
    ce01p[128 + pidx] = s1;
    cec[tid] = s0 * attw[tid];
    cep[tid] = s1 * attw[tid];
    __syncthreads();
    if (tid < 64) {
      float p0 = cec[tid] + cec[tid + 64];
      float p1 = cep[tid] + cep[tid + 64];
#pragma unroll
      for (int off = 32; off >= 1; off >>= 1) {
        p0 += __shfl_xor(p0, off);
        p1 += __shfl_xor(p1, off);
      }
      if (tid == 0) { cs[0] = 0.5f * p0; cs[1] = 0.5f * p1; }
    }
    for (int i = 0; i < 128; i++) {
      const int pi = (i & 15) * 8 + (i >> 4);       // p(i): permuted k-row
      Wpp[pi * 128 + tid] = l1w[i * 128 + tid] + l1w[16384 + i * 128 + tid];
    }
  }
}

// ---------------------------------------------------------------------------
// K4a: softmax over 32 neighbor scores + fp8 weighted row gather (p-space).
// One half-wave per b; lane t covers p-cols 4t..4t+3 (one uint). Scores fp32.
// ---------------------------------------------------------------------------
__global__ __launch_bounds__(256) void k4a_attn(const unsigned char* __restrict__ fe8,
    const float* __restrict__ q, const float* __restrict__ adj,
    const int* __restrict__ history, const float* __restrict__ cs,
    const float* __restrict__ attb_p, const float* __restrict__ ce01p,
    float* __restrict__ agg)
{
  const int tid = threadIdx.x;
  const int lane = tid & 63;
  const int wv = tid >> 6;
  const int half = lane >> 5;
  const int t = lane & 31;
  const int b = blockIdx.x * 8 + wv * 2 + half;

  const int n_my = history[b * 32 + t];
  const float a0 = adj[n_my];
  const float a1 = adj[NN + n_my];
  const float sc = q[n_my] + a0 * cs[0] + a1 * cs[1] + attb_p[0];
  float m = sc;
#pragma unroll
  for (int off = 16; off >= 1; off >>= 1) m = fmaxf(m, __shfl_xor(m, off, 32));
  const float e = expf(sc - m);
  float sum = e;
#pragma unroll
  for (int off = 16; off >= 1; off >>= 1) sum += __shfl_xor(sum, off, 32);
  const float att = e / sum;
  float p0 = att * a0, p1 = att * a1;
#pragma unroll
  for (int off = 16; off >= 1; off >>= 1) {
    p0 += __shfl_xor(p0, off, 32);
    p1 += __shfl_xor(p1, off, 32);
  }

  float4 acc = make_float4(0.f, 0.f, 0.f, 0.f);
#pragma unroll
  for (int k = 0; k < 32; k++) {
    const int nk = __shfl(n_my, k, 32);
    const float ak = __shfl(att, k, 32);
    const unsigned u = *reinterpret_cast<const unsigned*>(&fe8[(size_t)nk * 128 + t * 4]);
    const floatx2 lo = __builtin_amdgcn_cvt_pk_f32_fp8(u, false);
    const floatx2 hi = __builtin_amdgcn_cvt_pk_f32_fp8(u, true);
    acc.x = fmaf(ak, lo[0], acc.x);
    acc.y = fmaf(ak, lo[1], acc.y);
    acc.z = fmaf(ak, hi[0], acc.z);
    acc.w = fmaf(ak, hi[1], acc.w);
  }
  const int col = t * 4;
  const float4 c0 = *reinterpret_cast<const float4*>(&ce01p[col]);
  const float4 c1 = *reinterpret_cast<const float4*>(&ce01p[128 + col]);
  float4 o;
  o.x = 0.5f * (acc.x + p0 * c0.x + p1 * c1.x);
  o.y = 0.5f * (acc.y + p0 * c0.y + p1 * c1.y);
  o.z = 0.5f * (acc.z + p0 * c0.z + p1 * c1.z);
  o.w = 0.5f * (acc.w + p0 * c0.w + p1 * c1.w);
  *reinterpret_cast<float4*>(&agg[(size_t)b * 128 + col]) = o;
}

// K4b: out = relu(aggP @ Wpp + l1b); preds vs latTab rows (k in p-space)
__global__ __launch_bounds__(256) void k4b_out(const float* __restrict__ agg,
    const float* __restrict__ Wpp, const float* __restrict__ l1b,
    const float* __restrict__ latTab,
    const int* __restrict__ cr, const int* __restrict__ cn, const int* __restrict__ pa,
    float* __restrict__ out)
{
  __shared__ __align__(16) float AT[64][128];
  __shared__ __align__(16) float WT[64][128];
  const int tid = threadIdx.x;
  const int tx = tid & 15, ty = tid >> 4;
  const int rowbase = blockIdx.x * 128;
  float acc[8][8];
  gemm_main<2>(agg, 128, BB - 1, Wpp, rowbase, tid, AT, WT, acc);

  int* latIdx = reinterpret_cast<int*>(&AT[0][0]);
  if (tid < 128) {
    const int b = rowbase + tid;
    latIdx[tid * 2]     = (cr[b] * 10 + pa[b]) * 128;
    latIdx[tid * 2 + 1] = (cn[b] * 10 + pa[b]) * 128;
  }
  __syncthreads();

  const float4 b0 = *reinterpret_cast<const float4*>(&l1b[tx * 4]);
  const float4 b1 = *reinterpret_cast<const float4*>(&l1b[tx * 4 + 64]);
  const float bb[8] = {b0.x, b0.y, b0.z, b0.w, b1.x, b1.y, b1.z, b1.w};
#pragma unroll
  for (int i = 0; i < 8; i++) {
    const int r = (i < 4) ? (ty * 4 + i) : (64 + ty * 4 + (i - 4));
    const int b = rowbase + r;
    const int ir = latIdx[r * 2], in_ = latIdx[r * 2 + 1];
    const float4 lr0 = *reinterpret_cast<const float4*>(&latTab[ir + tx * 4]);
    const float4 lr1 = *reinterpret_cast<const float4*>(&latTab[ir + tx * 4 + 64]);
    const float4 ln0 = *reinterpret_cast<const float4*>(&latTab[in_ + tx * 4]);
    const float4 ln1 = *reinterpret_cast<const float4*>(&latTab[in_ + tx * 4 + 64]);
    const float lr[8] = {lr0.x, lr0.y, lr0.z, lr0.w, lr1.x, lr1.y, lr1.z, lr1.w};
    const float ln[8] = {ln0.x, ln0.y, ln0.z, ln0.w, ln1.x, ln1.y, ln1.z, ln1.w};
    float pr = 0.f, pn = 0.f;
#pragma unroll
    for (int j = 0; j < 8; j++) {
      const float v = fmaxf(acc[i][j] + bb[j], 0.f);
      pr = fmaf(v, lr[j], pr);
      pn = fmaf(v, ln[j], pn);
    }
    pr += __shfl_down(pr, 8, 16); pr += __shfl_down(pr, 4, 16);
    pr += __shfl_down(pr, 2, 16); pr += __shfl_down(pr, 1, 16);
    pn += __shfl_down(pn, 8, 16); pn += __shfl_down(pn, 4, 16);
    pn += __shfl_down(pn, 2, 16); pn += __shfl_down(pn, 1, 16);
    if (tx == 0) { out[b] = pr; out[BB + b] = pn; }
  }
}

extern "C" void kernel_launch(void* const* d_in, const int* in_sizes, int n_in,
                              void* d_out, int out_size, void* d_ws, size_t ws_size,
                              hipStream_t stream) {
  const float* feat  = (const float*)d_in[0];   // [N,F]
  const float* adj   = (const float*)d_in[1];   // [M,N]
  const int*   hist  = (const int*)d_in[2];     // [B,K]
  // d_in[3] item_id unused by reference
  const int*   cr    = (const int*)d_in[4];
  const int*   cn    = (const int*)d_in[5];
  const int*   pa    = (const int*)d_in[6];
  const float* wemb  = (const float*)d_in[7];   // [F,D]
  const float* bemb  = (const float*)d_in[8];   // [D]
  const float* wchar = (const float*)d_in[9];   // [2D,D]
  const float* attw  = (const float*)d_in[10];  // [D]
  const float* attb  = (const float*)d_in[11];  // [1]
  const float* l1w   = (const float*)d_in[12];  // [2D,D]
  const float* l1b   = (const float*)d_in[13];  // [D]
  float* out = (float*)d_out;
  float* ws  = (float*)d_ws;

  float* q     = ws + OFF_Q;
  float* ce    = ws + OFF_CE;
  float* lat   = ws + OFF_LAT;
  float* Wpp   = ws + OFF_WPP;
  float* ce01p = ws + OFF_CE01;
  float* cs    = ws + OFF_CS;
  float* agg   = ws + OFF_AGG;
  unsigned char* fe8 = (unsigned char*)(ws + OFF_FE8);
  short* wf    = (short*)(ws + OFF_WF);

  hipMemsetAsync(ce, 0, 1280 * sizeof(float), stream);
  k0_wprep<<<16, 256, 0, stream>>>(wemb, wf);
  k1_fused<<<NB1, 128, 0, stream>>>(feat, wf, bemb, attw, adj, q, fe8, ce);
  k3_prep<<<21, 128, 0, stream>>>(ce, wchar, attw, l1w, lat, Wpp, ce01p, cs);
  k4a_attn<<<4096, 256, 0, stream>>>(fe8, q, adj, hist, cs, attb, ce01p, agg);
  k4b_out<<<256, 256, 0, stream>>>(agg, Wpp, l1b, lat, cr, cn, pa, out);
}

// Round 6
// 275.031 us; speedup vs baseline: 1.6843x; 1.1317x over previous
//
#include <hip/hip_runtime.h>
#include <cmath>

#define NN 100000   // nodes
#define FF 256      // feature dim
#define DDIM 128    // embedding dim
#define MM 10       // categories
#define BB 32768    // batch
#define KK 32       // neighbors
#define NB1 782     // k1 blocks (128 rows each)
#define NREP 64     // ce replicas

// workspace layout (float offsets)
#define OFF_Q     0          // [NN] q
#define OFF_CEREP 100096     // [64][1280] ce replicas (memset 0 each launch)
#define OFF_CE    182016     // [10][128] reduced ce
#define OFF_LAT   183296     // [20][128] sigmoid lat table
#define OFF_CE01  185856     // [2][128] ce rows 0,1 in p-space
#define OFF_CS    186112     // [2] c0,c1 (+pad)
#define OFF_AGGB  186128     // [BB][128] bf16 (2,097,152 floats)
#define OFF_FE8   2283280    // [NN][128] bytes fp8 e4m3, p-space cols
#define OFF_WF    5483280    // W_emb bf16 frags, hi only (32768 shorts)
#define OFF_WPF   5499664    // Wp bf16 frags, p-space k rows (16384 shorts)
// total 5,507,856 floats = 21.0 MiB

typedef __attribute__((ext_vector_type(8))) short bf16x8;
typedef __attribute__((ext_vector_type(4))) float floatx4;
typedef __attribute__((ext_vector_type(2))) float floatx2;

__device__ __forceinline__ unsigned short f2bf(float x) {
  union { float f; unsigned u; } v; v.f = x;
  unsigned r = v.u + 0x7FFFu + ((v.u >> 16) & 1u);   // RNE
  return (unsigned short)(r >> 16);
}

__device__ __forceinline__ bf16x8 cvt8(float4 a, float4 b) {
  short h[8];
  h[0] = (short)f2bf(a.x); h[1] = (short)f2bf(a.y);
  h[2] = (short)f2bf(a.z); h[3] = (short)f2bf(a.w);
  h[4] = (short)f2bf(b.x); h[5] = (short)f2bf(b.y);
  h[6] = (short)f2bf(b.z); h[7] = (short)f2bf(b.w);
  return *reinterpret_cast<bf16x8*>(h);
}

// ---------------------------------------------------------------------------
// k0: prep B-operand fragment tables (bf16, 16x16x32 layout).
//  t < 4096:  wf  <- W_emb [256][128]:    elem = W[kk*32+(l>>4)*8+j][ct*16+(l&15)]
//  t >= 4096: wpf <- Wp = l1w[:128]+l1w[128:], with k-rows inverse-permuted so
//             that p-space agg columns line up: kp -> i = ((kp&7)<<4)|(kp>>3)
// ---------------------------------------------------------------------------
__global__ __launch_bounds__(256) void k0_wprep(const float* __restrict__ wemb,
                                                const float* __restrict__ l1w,
                                                short* __restrict__ wf,
                                                short* __restrict__ wpf)
{
  const int t = blockIdx.x * 256 + threadIdx.x;   // 0..6143
  if (t < 4096) {
    const int kk = t >> 9, rem = t & 511;
    const int ct = rem >> 6, l = rem & 63;
    const int n = ct * 16 + (l & 15);
    const int kbase = kk * 32 + (l >> 4) * 8;
    short hi[8];
#pragma unroll
    for (int j = 0; j < 8; j++) hi[j] = (short)f2bf(wemb[(kbase + j) * 128 + n]);
    *reinterpret_cast<int4*>(&wf[((kk * 8 + ct) * 64 + l) * 8]) = *reinterpret_cast<int4*>(hi);
  } else {
    const int t2 = t - 4096;                      // 0..2047
    const int kk = t2 >> 9, rem = t2 & 511;
    const int ct = rem >> 6, l = rem & 63;
    const int n = ct * 16 + (l & 15);
    short h[8];
#pragma unroll
    for (int j = 0; j < 8; j++) {
      const int kp = kk * 32 + (l >> 4) * 8 + j;
      const int i = ((kp & 7) << 4) | (kp >> 3);  // inverse of p(i)=(i&15)*8+(i>>4)
      h[j] = (short)f2bf(l1w[i * 128 + n] + l1w[(128 + i) * 128 + n]);
    }
    *reinterpret_cast<int4*>(&wpf[((kk * 8 + ct) * 64 + l) * 8]) = *reinterpret_cast<int4*>(h);
  }
}

// ---------------------------------------------------------------------------
// K1 (fused, single-bf16): per block of 128 rows (4 waves, 32 rows/wave):
//  fe = feat @ W_emb + b_emb  (one bf16 MFMA product; softmax is continuous,
//       bf16-level score noise ~0.002 abs is harmless)
//  q[n] = 0.5*dot(fe[n], attw)
//  fe8[n][p-space] e4m3, coalesced dwordx2 stores
//  ce partial via bf16 MFMA on LDS tile -> atomicAdd into cerep[blk&63]
// A loads: global->reg, depth-2 prefetch.
// ---------------------------------------------------------------------------
__global__ __launch_bounds__(256) void k1_fused(const float* __restrict__ feat,
    const short* __restrict__ wf, const float* __restrict__ bemb,
    const float* __restrict__ attw, const float* __restrict__ adj,
    float* __restrict__ q, unsigned char* __restrict__ fe8,
    float* __restrict__ cerep)
{
  __shared__ __align__(16) unsigned char ldst[128 * 272];  // bf16 tile [col][row0..127]
  const int tid = threadIdx.x;
  const int wv = tid >> 6, l = tid & 63;
  const int lane16 = l & 15, quad = l >> 4;
  const int rowbase = blockIdx.x * 128 + wv * 32;

  floatx4 acc[2][8];
#pragma unroll
  for (int rt = 0; rt < 2; rt++)
#pragma unroll
    for (int ct = 0; ct < 8; ct++) acc[rt][ct] = floatx4{0.f, 0.f, 0.f, 0.f};

  int r0 = rowbase + lane16;      if (r0 > NN - 1) r0 = NN - 1;
  int r1 = rowbase + 16 + lane16; if (r1 > NN - 1) r1 = NN - 1;
  const float* pa0 = &feat[(size_t)r0 * 256 + quad * 8];
  const float* pa1 = &feat[(size_t)r1 * 256 + quad * 8];

  // depth-2 prefetch buffers [parity][row][half]
  float4 pb[2][2][2];
  pb[0][0][0] = *reinterpret_cast<const float4*>(pa0);
  pb[0][0][1] = *reinterpret_cast<const float4*>(pa0 + 4);
  pb[0][1][0] = *reinterpret_cast<const float4*>(pa1);
  pb[0][1][1] = *reinterpret_cast<const float4*>(pa1 + 4);
  pb[1][0][0] = *reinterpret_cast<const float4*>(pa0 + 32);
  pb[1][0][1] = *reinterpret_cast<const float4*>(pa0 + 36);
  pb[1][1][0] = *reinterpret_cast<const float4*>(pa1 + 32);
  pb[1][1][1] = *reinterpret_cast<const float4*>(pa1 + 36);

  for (int kk = 0; kk < 8; kk++) {
    const int par = kk & 1;
    const bf16x8 a0 = cvt8(pb[par][0][0], pb[par][0][1]);
    const bf16x8 a1 = cvt8(pb[par][1][0], pb[par][1][1]);
    if (kk < 6) {
      pb[par][0][0] = *reinterpret_cast<const float4*>(pa0 + (kk + 2) * 32);
      pb[par][0][1] = *reinterpret_cast<const float4*>(pa0 + (kk + 2) * 32 + 4);
      pb[par][1][0] = *reinterpret_cast<const float4*>(pa1 + (kk + 2) * 32);
      pb[par][1][1] = *reinterpret_cast<const float4*>(pa1 + (kk + 2) * 32 + 4);
    }
    const short* wb = &wf[kk * 4096 + l * 8];
#pragma unroll
    for (int ct = 0; ct < 8; ct++) {
      const bf16x8 bh = *reinterpret_cast<const bf16x8*>(&wb[ct * 512]);
      acc[0][ct] = __builtin_amdgcn_mfma_f32_16x16x32_bf16(a0, bh, acc[0][ct], 0, 0, 0);
      acc[1][ct] = __builtin_amdgcn_mfma_f32_16x16x32_bf16(a1, bh, acc[1][ct], 0, 0, 0);
    }
  }

  // ---- epilogue: bias, q, fe8 (perm-packed). C layout: col = ct*16+lane16,
  // row = rowbase + rt*16 + quad*4 + reg.
  float bembv[8], attwv[8];
#pragma unroll
  for (int ct = 0; ct < 8; ct++) {
    bembv[ct] = bemb[ct * 16 + lane16];
    attwv[ct] = attw[ct * 16 + lane16];
  }
#pragma unroll
  for (int rt = 0; rt < 2; rt++) {
#pragma unroll
    for (int reg = 0; reg < 4; reg++) {
      const int r = rowbase + rt * 16 + quad * 4 + reg;
      float v[8]; float qp = 0.f;
#pragma unroll
      for (int ct = 0; ct < 8; ct++) {
        v[ct] = acc[rt][ct][reg] + bembv[ct];
        qp = fmaf(v[ct], attwv[ct], qp);
      }
      acc[rt][0][reg] = v[0]; acc[rt][1][reg] = v[1]; acc[rt][2][reg] = v[2]; acc[rt][3][reg] = v[3];
      acc[rt][4][reg] = v[4]; acc[rt][5][reg] = v[5]; acc[rt][6][reg] = v[6]; acc[rt][7][reg] = v[7];
      qp += __shfl_xor(qp, 1, 16);
      qp += __shfl_xor(qp, 2, 16);
      qp += __shfl_xor(qp, 4, 16);
      qp += __shfl_xor(qp, 8, 16);
      if (r < NN) {
        unsigned u0 = __builtin_amdgcn_cvt_pk_fp8_f32(v[0], v[1], 0, false);
        u0 = __builtin_amdgcn_cvt_pk_fp8_f32(v[2], v[3], u0, true);
        unsigned u1 = __builtin_amdgcn_cvt_pk_fp8_f32(v[4], v[5], 0, false);
        u1 = __builtin_amdgcn_cvt_pk_fp8_f32(v[6], v[7], u1, true);
        *reinterpret_cast<uint2*>(&fe8[(size_t)r * 128 + lane16 * 8]) = make_uint2(u0, u1);
        if (lane16 == 0) q[r] = 0.5f * qp;
      }
    }
  }
  // LDS bf16 tile [col][row], col stride 272 B; zero rows >= NN
#pragma unroll
  for (int rt = 0; rt < 2; rt++) {
#pragma unroll
    for (int rp = 0; rp < 2; rp++) {
      const int rloc = wv * 32 + rt * 16 + quad * 4 + rp * 2;
      const int g0 = blockIdx.x * 128 + rloc;
#pragma unroll
      for (int ct = 0; ct < 8; ct++) {
        const unsigned short h0 = (g0     < NN) ? f2bf(acc[rt][ct][rp * 2])     : (unsigned short)0;
        const unsigned short h1 = (g0 + 1 < NN) ? f2bf(acc[rt][ct][rp * 2 + 1]) : (unsigned short)0;
        const unsigned pk = (unsigned)h0 | ((unsigned)h1 << 16);
        *reinterpret_cast<unsigned*>(&ldst[(ct * 16 + lane16) * 272 + rloc * 2]) = pk;
      }
    }
  }
  __syncthreads();

  // ce partial: [10(pad16)][128] = adj[., block rows] @ tile -> cerep atomicAdd
  floatx4 cacc[2];
  cacc[0] = floatx4{0.f, 0.f, 0.f, 0.f};
  cacc[1] = floatx4{0.f, 0.f, 0.f, 0.f};
  const int mclamp = (lane16 < 10) ? lane16 : 9;
#pragma unroll
  for (int kc = 0; kc < 4; kc++) {
    int n0 = blockIdx.x * 128 + kc * 32 + quad * 8;
    if (n0 > NN - 8) n0 = NN - 8;               // clamped garbage x zero tile rows
    const float4 f0 = *reinterpret_cast<const float4*>(&adj[(size_t)mclamp * NN + n0]);
    const float4 f1 = *reinterpret_cast<const float4*>(&adj[(size_t)mclamp * NN + n0 + 4]);
    const bf16x8 afr = cvt8(f0, f1);
#pragma unroll
    for (int tt = 0; tt < 2; tt++) {
      const int col = (wv * 2 + tt) * 16 + lane16;
      const bf16x8 bfr = *reinterpret_cast<const bf16x8*>(
          &ldst[col * 272 + (kc * 32 + quad * 8) * 2]);
      cacc[tt] = __builtin_amdgcn_mfma_f32_16x16x32_bf16(afr, bfr, cacc[tt], 0, 0, 0);
    }
  }
  float* myrep = &cerep[(blockIdx.x & (NREP - 1)) * 1280];
#pragma unroll
  for (int tt = 0; tt < 2; tt++) {
#pragma unroll
    for (int reg = 0; reg < 4; reg++) {
      const int m = quad * 4 + reg;
      if (m < 10)
        atomicAdd(&myrep[m * 128 + (wv * 2 + tt) * 16 + lane16], cacc[tt][reg]);
    }
  }
}

// k3r: reduce 64 ce replicas -> ce[1280]
__global__ __launch_bounds__(256) void k3r_reduce(const float* __restrict__ cerep,
                                                  float* __restrict__ ce)
{
  const int o = blockIdx.x * 256 + threadIdx.x;   // 0..1279
  if (o < 1280) {
    float s = 0.f;
#pragma unroll 8
    for (int r = 0; r < NREP; r++) s += cerep[r * 1280 + o];
    ce[o] = s;
  }
}

// K3: blocks 0..19 lat rows from ce (L2-hot, 5 KB); block 20: ce01p, cs
__global__ __launch_bounds__(128) void k3_prep(const float* __restrict__ ce,
    const float* __restrict__ wchar, const float* __restrict__ attw,
    float* __restrict__ latTab, float* __restrict__ ce01p, float* __restrict__ cs)
{
  const int blk = blockIdx.x, tid = threadIdx.x;
  __shared__ float cec[128], cep[128];
  if (blk < 20) {
    const int c = blk / 10, p = blk % 10;
    cec[tid] = ce[c * 128 + tid];
    cep[tid] = ce[p * 128 + tid];
    __syncthreads();
    float s = 0.f;
#pragma unroll 4
    for (int j = 0; j < 128; j++) {
      s = fmaf(cec[j], wchar[j * 128 + tid], s);
      s = fmaf(cep[j], wchar[(128 + j) * 128 + tid], s);
    }
    latTab[blk * 128 + tid] = 1.f / (1.f + expf(-s));
  } else {
    const float s0 = ce[tid];
    const float s1 = ce[128 + tid];
    const int pidx = (tid & 15) * 8 + (tid >> 4);   // p(c)
    ce01p[pidx] = s0;
    ce01p[128 + pidx] = s1;
    cec[tid] = s0 * attw[tid];
    cep[tid] = s1 * attw[tid];
    __syncthreads();
    if (tid < 64) {
      float p0 = cec[tid] + cec[tid + 64];
      float p1 = cep[tid] + cep[tid + 64];
#pragma unroll
      for (int off = 32; off >= 1; off >>= 1) {
        p0 += __shfl_xor(p0, off);
        p1 += __shfl_xor(p1, off);
      }
      if (tid == 0) { cs[0] = 0.5f * p0; cs[1] = 0.5f * p1; }
    }
  }
}

// ---------------------------------------------------------------------------
// K4a: softmax over 32 neighbor scores + fp8 weighted row gather (p-space).
// One half-wave per b; lane t covers p-cols 4t..4t+3. agg stored bf16.
// ---------------------------------------------------------------------------
__global__ __launch_bounds__(256) void k4a_attn(const unsigned char* __restrict__ fe8,
    const float* __restrict__ q, const float* __restrict__ adj,
    const int* __restrict__ history, const float* __restrict__ cs,
    const float* __restrict__ attb_p, const float* __restrict__ ce01p,
    short* __restrict__ aggb)
{
  const int tid = threadIdx.x;
  const int lane = tid & 63;
  const int wv = tid >> 6;
  const int half = lane >> 5;
  const int t = lane & 31;
  const int b = blockIdx.x * 8 + wv * 2 + half;

  const int n_my = history[b * 32 + t];
  const float a0 = adj[n_my];
  const float a1 = adj[NN + n_my];
  const float sc = q[n_my] + a0 * cs[0] + a1 * cs[1] + attb_p[0];
  float m = sc;
#pragma unroll
  for (int off = 16; off >= 1; off >>= 1) m = fmaxf(m, __shfl_xor(m, off, 32));
  const float e = expf(sc - m);
  float sum = e;
#pragma unroll
  for (int off = 16; off >= 1; off >>= 1) sum += __shfl_xor(sum, off, 32);
  const float att = e / sum;
  float p0 = att * a0, p1 = att * a1;
#pragma unroll
  for (int off = 16; off >= 1; off >>= 1) {
    p0 += __shfl_xor(p0, off, 32);
    p1 += __shfl_xor(p1, off, 32);
  }

  float4 acc = make_float4(0.f, 0.f, 0.f, 0.f);
#pragma unroll
  for (int k = 0; k < 32; k++) {
    const int nk = __shfl(n_my, k, 32);
    const float ak = __shfl(att, k, 32);
    const unsigned u = *reinterpret_cast<const unsigned*>(&fe8[(size_t)nk * 128 + t * 4]);
    const floatx2 lo = __builtin_amdgcn_cvt_pk_f32_fp8(u, false);
    const floatx2 hi = __builtin_amdgcn_cvt_pk_f32_fp8(u, true);
    acc.x = fmaf(ak, lo[0], acc.x);
    acc.y = fmaf(ak, lo[1], acc.y);
    acc.z = fmaf(ak, hi[0], acc.z);
    acc.w = fmaf(ak, hi[1], acc.w);
  }
  const int col = t * 4;
  const float4 c0 = *reinterpret_cast<const float4*>(&ce01p[col]);
  const float4 c1 = *reinterpret_cast<const float4*>(&ce01p[128 + col]);
  const float ox = 0.5f * (acc.x + p0 * c0.x + p1 * c1.x);
  const float oy = 0.5f * (acc.y + p0 * c0.y + p1 * c1.y);
  const float oz = 0.5f * (acc.z + p0 * c0.z + p1 * c1.z);
  const float ow = 0.5f * (acc.w + p0 * c0.w + p1 * c1.w);
  const unsigned lo_ = (unsigned)f2bf(ox) | ((unsigned)f2bf(oy) << 16);
  const unsigned hi_ = (unsigned)f2bf(oz) | ((unsigned)f2bf(ow) << 16);
  *reinterpret_cast<uint2*>(&aggb[(size_t)b * 128 + col]) = make_uint2(lo_, hi_);
}

// ---------------------------------------------------------------------------
// K4b: out = relu(aggb @ wpf + l1b); pred_r/pred_n = dot(latTab rows, out).
// bf16 MFMA, no LDS; 4 waves x 32 rows; epilogue in C-layout.
// ---------------------------------------------------------------------------
__global__ __launch_bounds__(256) void k4b_mfma(const short* __restrict__ aggb,
    const short* __restrict__ wpf, const float* __restrict__ l1b,
    const float* __restrict__ latTab,
    const int* __restrict__ cr, const int* __restrict__ cn, const int* __restrict__ pa,
    float* __restrict__ out)
{
  const int tid = threadIdx.x;
  const int wv = tid >> 6, l = tid & 63;
  const int lane16 = l & 15, quad = l >> 4;
  const int rowbase = blockIdx.x * 128 + wv * 32;   // BB = 256*128 exact
  const int r0 = rowbase + lane16;
  const int r1 = r0 + 16;

  floatx4 acc[2][8];
#pragma unroll
  for (int rt = 0; rt < 2; rt++)
#pragma unroll
    for (int ct = 0; ct < 8; ct++) acc[rt][ct] = floatx4{0.f, 0.f, 0.f, 0.f};

#pragma unroll
  for (int kk = 0; kk < 4; kk++) {
    const bf16x8 a0 = *reinterpret_cast<const bf16x8*>(&aggb[(size_t)r0 * 128 + kk * 32 + quad * 8]);
    const bf16x8 a1 = *reinterpret_cast<const bf16x8*>(&aggb[(size_t)r1 * 128 + kk * 32 + quad * 8]);
    const short* wb = &wpf[kk * 4096 + l * 8];
#pragma unroll
    for (int ct = 0; ct < 8; ct++) {
      const bf16x8 bh = *reinterpret_cast<const bf16x8*>(&wb[ct * 512]);
      acc[0][ct] = __builtin_amdgcn_mfma_f32_16x16x32_bf16(a0, bh, acc[0][ct], 0, 0, 0);
      acc[1][ct] = __builtin_amdgcn_mfma_f32_16x16x32_bf16(a1, bh, acc[1][ct], 0, 0, 0);
    }
  }

  float bb[8];
#pragma unroll
  for (int ct = 0; ct < 8; ct++) bb[ct] = l1b[ct * 16 + lane16];
#pragma unroll
  for (int rt = 0; rt < 2; rt++) {
#pragma unroll
    for (int reg = 0; reg < 4; reg++) {
      const int r = rowbase + rt * 16 + quad * 4 + reg;
      const int ir  = (cr[r] * 10 + pa[r]) * 128;
      const int in_ = (cn[r] * 10 + pa[r]) * 128;
      float pr = 0.f, pn = 0.f;
#pragma unroll
      for (int ct = 0; ct < 8; ct++) {
        const float v = fmaxf(acc[rt][ct][reg] + bb[ct], 0.f);
        pr = fmaf(v, latTab[ir  + ct * 16 + lane16], pr);
        pn = fmaf(v, latTab[in_ + ct * 16 + lane16], pn);
      }
      pr += __shfl_xor(pr, 1, 16); pr += __shfl_xor(pr, 2, 16);
      pr += __shfl_xor(pr, 4, 16); pr += __shfl_xor(pr, 8, 16);
      pn += __shfl_xor(pn, 1, 16); pn += __shfl_xor(pn, 2, 16);
      pn += __shfl_xor(pn, 4, 16); pn += __shfl_xor(pn, 8, 16);
      if (lane16 == 0) { out[r] = pr; out[BB + r] = pn; }
    }
  }
}

extern "C" void kernel_launch(void* const* d_in, const int* in_sizes, int n_in,
                              void* d_out, int out_size, void* d_ws, size_t ws_size,
                              hipStream_t stream) {
  const float* feat  = (const float*)d_in[0];   // [N,F]
  const float* adj   = (const float*)d_in[1];   // [M,N]
  const int*   hist  = (const int*)d_in[2];     // [B,K]
  // d_in[3] item_id unused by reference
  const int*   cr    = (const int*)d_in[4];
  const int*   cn    = (const int*)d_in[5];
  const int*   pa    = (const int*)d_in[6];
  const float* wemb  = (const float*)d_in[7];   // [F,D]
  const float* bemb  = (const float*)d_in[8];   // [D]
  const float* wchar = (const float*)d_in[9];   // [2D,D]
  const float* attw  = (const float*)d_in[10];  // [D]
  const float* attb  = (const float*)d_in[11];  // [1]
  const float* l1w   = (const float*)d_in[12];  // [2D,D]
  const float* l1b   = (const float*)d_in[13];  // [D]
  float* out = (float*)d_out;
  float* ws  = (float*)d_ws;

  float* q     = ws + OFF_Q;
  float* cerep = ws + OFF_CEREP;
  float* ce    = ws + OFF_CE;
  float* lat   = ws + OFF_LAT;
  float* ce01p = ws + OFF_CE01;
  float* cs    = ws + OFF_CS;
  short* aggb  = (short*)(ws + OFF_AGGB);
  unsigned char* fe8 = (unsigned char*)(ws + OFF_FE8);
  short* wf    = (short*)(ws + OFF_WF);
  short* wpf   = (short*)(ws + OFF_WPF);

  hipMemsetAsync(cerep, 0, NREP * 1280 * sizeof(float), stream);
  k0_wprep<<<24, 256, 0, stream>>>(wemb, l1w, wf, wpf);
  k1_fused<<<NB1, 256, 0, stream>>>(feat, wf, bemb, attw, adj, q, fe8, cerep);
  k3r_reduce<<<5, 256, 0, stream>>>(cerep, ce);
  k3_prep<<<21, 128, 0, stream>>>(ce, wchar, attw, lat, ce01p, cs);
  k4a_attn<<<4096, 256, 0, stream>>>(fe8, q, adj, hist, cs, attb, ce01p, aggb);
  k4b_mfma<<<256, 256, 0, stream>>>(aggb, wpf, l1b, lat, cr, cn, pa, out);
}

// Round 7
// 268.673 us; speedup vs baseline: 1.7241x; 1.0237x over previous
//
#include <hip/hip_runtime.h>
#include <cmath>

#define NN 100000   // nodes
#define FF 256      // feature dim
#define DDIM 128    // embedding dim
#define MM 10       // categories
#define BB 32768    // batch
#define KK 32       // neighbors
#define NB1 1563    // k1 blocks (64 rows each)
#define NREP 64     // ce replicas

// workspace layout (float offsets)
#define OFF_Q     0          // [NN] q
#define OFF_CEREP 100096     // [64][1280] ce replicas (memset 0 each launch)
#define OFF_CE    182016     // [10][128] reduced ce
#define OFF_LAT   183296     // [20][128] sigmoid lat table
#define OFF_CE01  185856     // [2][128] ce rows 0,1 in p-space
#define OFF_CS    186112     // [2] c0,c1 (+pad)
#define OFF_AGGB  186128     // [BB][128] bf16 (2,097,152 floats)
#define OFF_FE8   2283280    // [NN][128] bytes fp8 e4m3, p-space cols
#define OFF_WF    5483280    // W_emb bf16 frags (32768 shorts)
#define OFF_WPF   5499664    // Wp bf16 frags, p-space k rows (16384 shorts)
// total 5,507,856 floats = 21.0 MiB

typedef __attribute__((ext_vector_type(8))) short bf16x8;
typedef __attribute__((ext_vector_type(4))) float floatx4;
typedef __attribute__((ext_vector_type(2))) float floatx2;

__device__ __forceinline__ unsigned short f2bf(float x) {
  union { float f; unsigned u; } v; v.f = x;
  unsigned r = v.u + 0x7FFFu + ((v.u >> 16) & 1u);   // RNE
  return (unsigned short)(r >> 16);
}

__device__ __forceinline__ bf16x8 cvt8(float4 a, float4 b) {
  short h[8];
  h[0] = (short)f2bf(a.x); h[1] = (short)f2bf(a.y);
  h[2] = (short)f2bf(a.z); h[3] = (short)f2bf(a.w);
  h[4] = (short)f2bf(b.x); h[5] = (short)f2bf(b.y);
  h[6] = (short)f2bf(b.z); h[7] = (short)f2bf(b.w);
  return *reinterpret_cast<bf16x8*>(h);
}

// ---------------------------------------------------------------------------
// k0: prep B-operand fragment tables (bf16, 16x16x32 layout).
//  t < 4096:  wf  <- W_emb [256][128]:    elem = W[kk*32+(l>>4)*8+j][ct*16+(l&15)]
//  t >= 4096: wpf <- Wp = l1w[:128]+l1w[128:], k-rows inverse-permuted (p-space)
// ---------------------------------------------------------------------------
__global__ __launch_bounds__(256) void k0_wprep(const float* __restrict__ wemb,
                                                const float* __restrict__ l1w,
                                                short* __restrict__ wf,
                                                short* __restrict__ wpf)
{
  const int t = blockIdx.x * 256 + threadIdx.x;   // 0..6143
  if (t < 4096) {
    const int kk = t >> 9, rem = t & 511;
    const int ct = rem >> 6, l = rem & 63;
    const int n = ct * 16 + (l & 15);
    const int kbase = kk * 32 + (l >> 4) * 8;
    short hi[8];
#pragma unroll
    for (int j = 0; j < 8; j++) hi[j] = (short)f2bf(wemb[(kbase + j) * 128 + n]);
    *reinterpret_cast<int4*>(&wf[((kk * 8 + ct) * 64 + l) * 8]) = *reinterpret_cast<int4*>(hi);
  } else {
    const int t2 = t - 4096;                      // 0..2047
    const int kk = t2 >> 9, rem = t2 & 511;
    const int ct = rem >> 6, l = rem & 63;
    const int n = ct * 16 + (l & 15);
    short h[8];
#pragma unroll
    for (int j = 0; j < 8; j++) {
      const int kp = kk * 32 + (l >> 4) * 8 + j;
      const int i = ((kp & 7) << 4) | (kp >> 3);  // inverse of p(i)=(i&15)*8+(i>>4)
      h[j] = (short)f2bf(l1w[i * 128 + n] + l1w[(128 + i) * 128 + n]);
    }
    *reinterpret_cast<int4*>(&wpf[((kk * 8 + ct) * 64 + l) * 8]) = *reinterpret_cast<int4*>(h);
  }
}

// ---------------------------------------------------------------------------
// K1 (fused): 1563 blocks x 256 thr; 64 rows/block, 16 rows/wave (1 row/lane).
//  fe = feat @ W_emb + b_emb  (bf16 MFMA), q, fe8 (p-space), ce partial.
// A-stream: 16 float4/lane, depth-4 ring preload (>=8 loads in flight) for MLP.
// ---------------------------------------------------------------------------
__global__ __launch_bounds__(256) void k1_fused(const float* __restrict__ feat,
    const short* __restrict__ wf, const float* __restrict__ bemb,
    const float* __restrict__ attw, const float* __restrict__ adj,
    float* __restrict__ q, unsigned char* __restrict__ fe8,
    float* __restrict__ cerep)
{
  __shared__ __align__(16) unsigned char ldst[128 * 144];  // bf16 tile [col][row0..63]
  const int tid = threadIdx.x;
  const int wv = tid >> 6, l = tid & 63;
  const int lane16 = l & 15, quad = l >> 4;
  const int rowbase = blockIdx.x * 64 + wv * 16;

  floatx4 acc[8];
#pragma unroll
  for (int ct = 0; ct < 8; ct++) acc[ct] = floatx4{0.f, 0.f, 0.f, 0.f};

  int r0 = rowbase + lane16; if (r0 > NN - 1) r0 = NN - 1;
  const float* pa = &feat[(size_t)r0 * 256 + quad * 8];

  float4 A[4][2];                       // depth-4 ring
#pragma unroll
  for (int i = 0; i < 4; i++) {
    A[i][0] = *reinterpret_cast<const float4*>(pa + i * 32);
    A[i][1] = *reinterpret_cast<const float4*>(pa + i * 32 + 4);
  }
#pragma unroll
  for (int kk = 0; kk < 8; kk++) {
    const bf16x8 a0 = cvt8(A[kk & 3][0], A[kk & 3][1]);
    if (kk < 4) {
      A[kk & 3][0] = *reinterpret_cast<const float4*>(pa + (kk + 4) * 32);
      A[kk & 3][1] = *reinterpret_cast<const float4*>(pa + (kk + 4) * 32 + 4);
    }
    const short* wb = &wf[kk * 4096 + l * 8];
#pragma unroll
    for (int ct = 0; ct < 8; ct++) {
      const bf16x8 bh = *reinterpret_cast<const bf16x8*>(&wb[ct * 512]);
      acc[ct] = __builtin_amdgcn_mfma_f32_16x16x32_bf16(a0, bh, acc[ct], 0, 0, 0);
    }
  }

  // ---- epilogue. C layout: col = ct*16+lane16, row = rowbase + quad*4 + reg.
  float bembv[8], attwv[8];
#pragma unroll
  for (int ct = 0; ct < 8; ct++) {
    bembv[ct] = bemb[ct * 16 + lane16];
    attwv[ct] = attw[ct * 16 + lane16];
  }
#pragma unroll
  for (int reg = 0; reg < 4; reg++) {
    const int r = rowbase + quad * 4 + reg;
    float v[8]; float qp = 0.f;
#pragma unroll
    for (int ct = 0; ct < 8; ct++) {
      v[ct] = acc[ct][reg] + bembv[ct];
      qp = fmaf(v[ct], attwv[ct], qp);
    }
    acc[0][reg] = v[0]; acc[1][reg] = v[1]; acc[2][reg] = v[2]; acc[3][reg] = v[3];
    acc[4][reg] = v[4]; acc[5][reg] = v[5]; acc[6][reg] = v[6]; acc[7][reg] = v[7];
    qp += __shfl_xor(qp, 1, 16);
    qp += __shfl_xor(qp, 2, 16);
    qp += __shfl_xor(qp, 4, 16);
    qp += __shfl_xor(qp, 8, 16);
    if (r < NN) {
      unsigned u0 = __builtin_amdgcn_cvt_pk_fp8_f32(v[0], v[1], 0, false);
      u0 = __builtin_amdgcn_cvt_pk_fp8_f32(v[2], v[3], u0, true);
      unsigned u1 = __builtin_amdgcn_cvt_pk_fp8_f32(v[4], v[5], 0, false);
      u1 = __builtin_amdgcn_cvt_pk_fp8_f32(v[6], v[7], u1, true);
      *reinterpret_cast<uint2*>(&fe8[(size_t)r * 128 + lane16 * 8]) = make_uint2(u0, u1);
      if (lane16 == 0) q[r] = 0.5f * qp;
    }
  }
  // LDS bf16 tile [col][row], col stride 144 B (2-way-free banks); zero rows >= NN
#pragma unroll
  for (int rp = 0; rp < 2; rp++) {
    const int rloc = wv * 16 + quad * 4 + rp * 2;
    const int g0 = blockIdx.x * 64 + rloc;
#pragma unroll
    for (int ct = 0; ct < 8; ct++) {
      const unsigned short h0 = (g0     < NN) ? f2bf(acc[ct][rp * 2])     : (unsigned short)0;
      const unsigned short h1 = (g0 + 1 < NN) ? f2bf(acc[ct][rp * 2 + 1]) : (unsigned short)0;
      const unsigned pk = (unsigned)h0 | ((unsigned)h1 << 16);
      *reinterpret_cast<unsigned*>(&ldst[(ct * 16 + lane16) * 144 + rloc * 2]) = pk;
    }
  }
  __syncthreads();

  // ce partial: [10(pad16)][128] = adj[., block rows] @ tile -> cerep atomicAdd
  floatx4 cacc[2];
  cacc[0] = floatx4{0.f, 0.f, 0.f, 0.f};
  cacc[1] = floatx4{0.f, 0.f, 0.f, 0.f};
  const int mclamp = (lane16 < 10) ? lane16 : 9;
#pragma unroll
  for (int kc = 0; kc < 2; kc++) {
    int n0 = blockIdx.x * 64 + kc * 32 + quad * 8;
    if (n0 > NN - 8) n0 = NN - 8;               // clamped garbage x zero tile rows
    const float4 f0 = *reinterpret_cast<const float4*>(&adj[(size_t)mclamp * NN + n0]);
    const float4 f1 = *reinterpret_cast<const float4*>(&adj[(size_t)mclamp * NN + n0 + 4]);
    const bf16x8 afr = cvt8(f0, f1);
#pragma unroll
    for (int tt = 0; tt < 2; tt++) {
      const int col = (wv * 2 + tt) * 16 + lane16;
      const bf16x8 bfr = *reinterpret_cast<const bf16x8*>(
          &ldst[col * 144 + (kc * 32 + quad * 8) * 2]);
      cacc[tt] = __builtin_amdgcn_mfma_f32_16x16x32_bf16(afr, bfr, cacc[tt], 0, 0, 0);
    }
  }
  float* myrep = &cerep[(blockIdx.x & (NREP - 1)) * 1280];
#pragma unroll
  for (int tt = 0; tt < 2; tt++) {
#pragma unroll
    for (int reg = 0; reg < 4; reg++) {
      const int m = quad * 4 + reg;
      if (m < 10)
        atomicAdd(&myrep[m * 128 + (wv * 2 + tt) * 16 + lane16], cacc[tt][reg]);
    }
  }
}

// k3r: reduce 64 ce replicas -> ce[1280]
__global__ __launch_bounds__(256) void k3r_reduce(const float* __restrict__ cerep,
                                                  float* __restrict__ ce)
{
  const int o = blockIdx.x * 256 + threadIdx.x;   // 0..1279
  if (o < 1280) {
    float s = 0.f;
#pragma unroll 8
    for (int r = 0; r < NREP; r++) s += cerep[r * 1280 + o];
    ce[o] = s;
  }
}

// K3: blocks 0..19 lat rows from ce (L2-hot, 5 KB); block 20: ce01p, cs
__global__ __launch_bounds__(128) void k3_prep(const float* __restrict__ ce,
    const float* __restrict__ wchar, const float* __restrict__ attw,
    float* __restrict__ latTab, float* __restrict__ ce01p, float* __restrict__ cs)
{
  const int blk = blockIdx.x, tid = threadIdx.x;
  __shared__ float cec[128], cep[128];
  if (blk < 20) {
    const int c = blk / 10, p = blk % 10;
    cec[tid] = ce[c * 128 + tid];
    cep[tid] = ce[p * 128 + tid];
    __syncthreads();
    float s = 0.f;
#pragma unroll 4
    for (int j = 0; j < 128; j++) {
      s = fmaf(cec[j], wchar[j * 128 + tid], s);
      s = fmaf(cep[j], wchar[(128 + j) * 128 + tid], s);
    }
    latTab[blk * 128 + tid] = 1.f / (1.f + expf(-s));
  } else {
    const float s0 = ce[tid];
    const float s1 = ce[128 + tid];
    const int pidx = (tid & 15) * 8 + (tid >> 4);   // p(c)
    ce01p[pidx] = s0;
    ce01p[128 + pidx] = s1;
    cec[tid] = s0 * attw[tid];
    cep[tid] = s1 * attw[tid];
    __syncthreads();
    if (tid < 64) {
      float p0 = cec[tid] + cec[tid + 64];
      float p1 = cep[tid] + cep[tid + 64];
#pragma unroll
      for (int off = 32; off >= 1; off >>= 1) {
        p0 += __shfl_xor(p0, off);
        p1 += __shfl_xor(p1, off);
      }
      if (tid == 0) { cs[0] = 0.5f * p0; cs[1] = 0.5f * p1; }
    }
  }
}

// ---------------------------------------------------------------------------
// K4a: softmax over 32 neighbor scores + fp8 weighted row gather (p-space).
// One half-wave per b; lane t covers p-cols 4t..4t+3. agg stored bf16.
// ---------------------------------------------------------------------------
__global__ __launch_bounds__(256) void k4a_attn(const unsigned char* __restrict__ fe8,
    const float* __restrict__ q, const float* __restrict__ adj,
    const int* __restrict__ history, const float* __restrict__ cs,
    const float* __restrict__ attb_p, const float* __restrict__ ce01p,
    short* __restrict__ aggb)
{
  const int tid = threadIdx.x;
  const int lane = tid & 63;
  const int wv = tid >> 6;
  const int half = lane >> 5;
  const int t = lane & 31;
  const int b = blockIdx.x * 8 + wv * 2 + half;

  const int n_my = history[b * 32 + t];
  const float a0 = adj[n_my];
  const float a1 = adj[NN + n_my];
  const float sc = q[n_my] + a0 * cs[0] + a1 * cs[1] + attb_p[0];
  float m = sc;
#pragma unroll
  for (int off = 16; off >= 1; off >>= 1) m = fmaxf(m, __shfl_xor(m, off, 32));
  const float e = expf(sc - m);
  float sum = e;
#pragma unroll
  for (int off = 16; off >= 1; off >>= 1) sum += __shfl_xor(sum, off, 32);
  const float att = e / sum;
  float p0 = att * a0, p1 = att * a1;
#pragma unroll
  for (int off = 16; off >= 1; off >>= 1) {
    p0 += __shfl_xor(p0, off, 32);
    p1 += __shfl_xor(p1, off, 32);
  }

  float4 acc = make_float4(0.f, 0.f, 0.f, 0.f);
#pragma unroll
  for (int k = 0; k < 32; k++) {
    const int nk = __shfl(n_my, k, 32);
    const float ak = __shfl(att, k, 32);
    const unsigned u = *reinterpret_cast<const unsigned*>(&fe8[(size_t)nk * 128 + t * 4]);
    const floatx2 lo = __builtin_amdgcn_cvt_pk_f32_fp8(u, false);
    const floatx2 hi = __builtin_amdgcn_cvt_pk_f32_fp8(u, true);
    acc.x = fmaf(ak, lo[0], acc.x);
    acc.y = fmaf(ak, lo[1], acc.y);
    acc.z = fmaf(ak, hi[0], acc.z);
    acc.w = fmaf(ak, hi[1], acc.w);
  }
  const int col = t * 4;
  const float4 c0 = *reinterpret_cast<const float4*>(&ce01p[col]);
  const float4 c1 = *reinterpret_cast<const float4*>(&ce01p[128 + col]);
  const float ox = 0.5f * (acc.x + p0 * c0.x + p1 * c1.x);
  const float oy = 0.5f * (acc.y + p0 * c0.y + p1 * c1.y);
  const float oz = 0.5f * (acc.z + p0 * c0.z + p1 * c1.z);
  const float ow = 0.5f * (acc.w + p0 * c0.w + p1 * c1.w);
  const unsigned lo_ = (unsigned)f2bf(ox) | ((unsigned)f2bf(oy) << 16);
  const unsigned hi_ = (unsigned)f2bf(oz) | ((unsigned)f2bf(ow) << 16);
  *reinterpret_cast<uint2*>(&aggb[(size_t)b * 128 + col]) = make_uint2(lo_, hi_);
}

// ---------------------------------------------------------------------------
// K4b: out = relu(aggb @ wpf + l1b); pred_r/pred_n = dot(latTab rows, out).
// bf16 MFMA, no LDS; 4 waves x 32 rows; epilogue in C-layout.
// ---------------------------------------------------------------------------
__global__ __launch_bounds__(256) void k4b_mfma(const short* __restrict__ aggb,
    const short* __restrict__ wpf, const float* __restrict__ l1b,
    const float* __restrict__ latTab,
    const int* __restrict__ cr, const int* __restrict__ cn, const int* __restrict__ pa,
    float* __restrict__ out)
{
  const int tid = threadIdx.x;
  const int wv = tid >> 6, l = tid & 63;
  const int lane16 = l & 15, quad = l >> 4;
  const int rowbase = blockIdx.x * 128 + wv * 32;   // BB = 256*128 exact
  const int r0 = rowbase + lane16;
  const int r1 = r0 + 16;

  floatx4 acc[2][8];
#pragma unroll
  for (int rt = 0; rt < 2; rt++)
#pragma unroll
    for (int ct = 0; ct < 8; ct++) acc[rt][ct] = floatx4{0.f, 0.f, 0.f, 0.f};

#pragma unroll
  for (int kk = 0; kk < 4; kk++) {
    const bf16x8 a0 = *reinterpret_cast<const bf16x8*>(&aggb[(size_t)r0 * 128 + kk * 32 + quad * 8]);
    const bf16x8 a1 = *reinterpret_cast<const bf16x8*>(&aggb[(size_t)r1 * 128 + kk * 32 + quad * 8]);
    const short* wb = &wpf[kk * 4096 + l * 8];
#pragma unroll
    for (int ct = 0; ct < 8; ct++) {
      const bf16x8 bh = *reinterpret_cast<const bf16x8*>(&wb[ct * 512]);
      acc[0][ct] = __builtin_amdgcn_mfma_f32_16x16x32_bf16(a0, bh, acc[0][ct], 0, 0, 0);
      acc[1][ct] = __builtin_amdgcn_mfma_f32_16x16x32_bf16(a1, bh, acc[1][ct], 0, 0, 0);
    }
  }

  float bb[8];
#pragma unroll
  for (int ct = 0; ct < 8; ct++) bb[ct] = l1b[ct * 16 + lane16];
#pragma unroll
  for (int rt = 0; rt < 2; rt++) {
#pragma unroll
    for (int reg = 0; reg < 4; reg++) {
      const int r = rowbase + rt * 16 + quad * 4 + reg;
      const int ir  = (cr[r] * 10 + pa[r]) * 128;
      const int in_ = (cn[r] * 10 + pa[r]) * 128;
      float pr = 0.f, pn = 0.f;
#pragma unroll
      for (int ct = 0; ct < 8; ct++) {
        const float v = fmaxf(acc[rt][ct][reg] + bb[ct], 0.f);
        pr = fmaf(v, latTab[ir  + ct * 16 + lane16], pr);
        pn = fmaf(v, latTab[in_ + ct * 16 + lane16], pn);
      }
      pr += __shfl_xor(pr, 1, 16); pr += __shfl_xor(pr, 2, 16);
      pr += __shfl_xor(pr, 4, 16); pr += __shfl_xor(pr, 8, 16);
      pn += __shfl_xor(pn, 1, 16); pn += __shfl_xor(pn, 2, 16);
      pn += __shfl_xor(pn, 4, 16); pn += __shfl_xor(pn, 8, 16);
      if (lane16 == 0) { out[r] = pr; out[BB + r] = pn; }
    }
  }
}

extern "C" void kernel_launch(void* const* d_in, const int* in_sizes, int n_in,
                              void* d_out, int out_size, void* d_ws, size_t ws_size,
                              hipStream_t stream) {
  const float* feat  = (const float*)d_in[0];   // [N,F]
  const float* adj   = (const float*)d_in[1];   // [M,N]
  const int*   hist  = (const int*)d_in[2];     // [B,K]
  // d_in[3] item_id unused by reference
  const int*   cr    = (const int*)d_in[4];
  const int*   cn    = (const int*)d_in[5];
  const int*   pa    = (const int*)d_in[6];
  const float* wemb  = (const float*)d_in[7];   // [F,D]
  const float* bemb  = (const float*)d_in[8];   // [D]
  const float* wchar = (const float*)d_in[9];   // [2D,D]
  const float* attw  = (const float*)d_in[10];  // [D]
  const float* attb  = (const float*)d_in[11];  // [1]
  const float* l1w   = (const float*)d_in[12];  // [2D,D]
  const float* l1b   = (const float*)d_in[13];  // [D]
  float* out = (float*)d_out;
  float* ws  = (float*)d_ws;

  float* q     = ws + OFF_Q;
  float* cerep = ws + OFF_CEREP;
  float* ce    = ws + OFF_CE;
  float* lat   = ws + OFF_LAT;
  float* ce01p = ws + OFF_CE01;
  float* cs    = ws + OFF_CS;
  short* aggb  = (short*)(ws + OFF_AGGB);
  unsigned char* fe8 = (unsigned char*)(ws + OFF_FE8);
  short* wf    = (short*)(ws + OFF_WF);
  short* wpf   = (short*)(ws + OFF_WPF);

  hipMemsetAsync(cerep, 0, NREP * 1280 * sizeof(float), stream);
  k0_wprep<<<24, 256, 0, stream>>>(wemb, l1w, wf, wpf);
  k1_fused<<<NB1, 256, 0, stream>>>(feat, wf, bemb, attw, adj, q, fe8, cerep);
  k3r_reduce<<<5, 256, 0, stream>>>(cerep, ce);
  k3_prep<<<21, 128, 0, stream>>>(ce, wchar, attw, lat, ce01p, cs);
  k4a_attn<<<4096, 256, 0, stream>>>(fe8, q, adj, hist, cs, attb, ce01p, aggb);
  k4b_mfma<<<256, 256, 0, stream>>>(aggb, wpf, l1b, lat, cr, cn, pa, out);
}